// Round 15
// baseline (355.167 us; speedup 1.0000x reference)
//
#include <hip/hip_runtime.h>
#include <hip/hip_cooperative_groups.h>
#include <stdint.h>

// buildProposalTargetLayer — exact JAX replication (partitionable threefry).
// R15 = R14 with the phase-4 coverage bug fixed: B*2*NBKT = 262144 buckets
// but GRID*TPB = 131072 threads — R14 sorted only half the buckets (batches
// 8..15 unsorted -> absmax 883). Phase 4 is now a grid-stride loop.
// Phases: zero hist | mask | scan | scatter | bsort | sample, separated by
// grid.sync(). All math/PRNG identical to R12 (absmax 0.0 proven).
// The per-iteration 256MiB harness ws-poison fill (~39.5us @86% HBM peak)
// is fixed overhead outside our control.

namespace cg = cooperative_groups;

typedef uint32_t u32;

constexpr int B    = 16;
constexpr int R    = 20000;
constexpr int G    = 100;
constexpr int N    = R + G;    // 20100
constexpr int S    = 512;
constexpr int KFG  = 128;
constexpr int NBKT = 8192;     // bucket = key>>10 (23-bit keys), avg ~2.5/bucket
constexpr u32 SENT = 0xFFFFFFFFu;
constexpr int TPB  = 256;
constexpr int NBLK = (N + TPB - 1) / TPB;   // 79 mask chunks per batch
constexpr int CHNK = B * NBLK;              // 1264 (b,x) chunks
constexpr int GRID = 512;                   // 2 blocks/CU — always co-resident

// ---------------- threefry2x32 (20 rounds) ----------------
__device__ __forceinline__ void tf2x32(u32 k0, u32 k1, u32 x0, u32 x1,
                                       u32& o0, u32& o1) {
  u32 ks2 = k0 ^ k1 ^ 0x1BD11BDAu;
#define TFR(r) { x0 += x1; x1 = (x1 << (r)) | (x1 >> (32 - (r))); x1 ^= x0; }
  x0 += k0; x1 += k1;
  TFR(13) TFR(15) TFR(26) TFR(6)
  x0 += k1;  x1 += ks2 + 1u;
  TFR(17) TFR(29) TFR(16) TFR(24)
  x0 += ks2; x1 += k0 + 2u;
  TFR(13) TFR(15) TFR(26) TFR(6)
  x0 += k0;  x1 += k1 + 3u;
  TFR(17) TFR(29) TFR(16) TFR(24)
  x0 += k1;  x1 += ks2 + 4u;
  TFR(13) TFR(15) TFR(26) TFR(6)
  x0 += ks2; x1 += k0 + 5u;
#undef TFR
  o0 = x0; o1 = x1;
}

__device__ __forceinline__ void batch_key(int b, u32& kb0, u32& kb1) {
  tf2x32(0u, 42u, 0u, (u32)b, kb0, kb1);
}
__device__ __forceinline__ void sub_key(u32 kb0, u32 kb1, int j, u32& k0, u32& k1) {
  tf2x32(kb0, kb1, 0u, (u32)j, k0, k1);
}
__device__ __forceinline__ u32 rand_bits(u32 k0, u32 k1, int i) {
  u32 b0, b1;
  tf2x32(k0, k1, 0u, (u32)i, b0, b1);
  return b0 ^ b1;
}
__device__ __forceinline__ float bits_to_uniform(u32 bits) {
  return __uint_as_float((bits >> 9) | 0x3f800000u) - 1.0f;
}

// ---------------- fused cooperative kernel ----------------
__global__ __launch_bounds__(TPB) void
k_fused(const float* __restrict__ rois, const float* __restrict__ gts,
        const float* __restrict__ means, const float* __restrict__ stds,
        u32* __restrict__ ckey, u32* __restrict__ cnt, u32* __restrict__ cur,
        u32* __restrict__ minblkF, u32* __restrict__ minblkB,
        int* __restrict__ nfg, int* __restrict__ nbg,
        u32* __restrict__ slotF, u32* __restrict__ slotB,
        float* __restrict__ out) {
#pragma clang fp contract(off)
  __shared__ float4 gbox[G];
  __shared__ float garea[G];
  __shared__ float glab[G];
  __shared__ u32 wminF[TPB / 64], wminB[TPB / 64];
  __shared__ u32 sh[TPB];

  cg::grid_group grid = cg::this_grid();
  const int blk = blockIdx.x;
  const int tid = threadIdx.x;

  // ---------- phase 0: zero the bucket histogram ----------
  for (int i = blk * TPB + tid; i < B * 2 * NBKT; i += GRID * TPB)
    cnt[i] = 0u;
  grid.sync();

  // ---------- phase 1: mask (divide-free EXACT fg test + keys) ----------
  for (int c = blk; c < CHNK; c += GRID) {
    const int b = c / NBLK;
    const int x = c % NBLK;
    __syncthreads();   // fence previous iteration's gbox/garea reads
    if (tid < G) {
      const float* gp = gts + (size_t)(b * G + tid) * 5;
      float x1 = gp[0], y1 = gp[1], x2 = gp[2], y2 = gp[3];
      gbox[tid] = make_float4(x1, y1, x2, y2);
      garea[tid] = (x2 - x1 + 1.0f) * (y2 - y1 + 1.0f);
    }
    __syncthreads();

    const int n = x * TPB + tid;
    const bool valid = n < N;
    const int nl = valid ? n : 0;

    float ax1, ay1, ax2, ay2;
    if (nl < R) {
      const float* rp = rois + (size_t)(b * R + nl) * 5;
      ax1 = rp[1]; ay1 = rp[2]; ax2 = rp[3]; ay2 = rp[4];
    } else {
      const float* gp = gts + (size_t)(b * G + (nl - R)) * 5;
      ax1 = gp[0]; ay1 = gp[1]; ax2 = gp[2]; ay2 = gp[3];
    }
    const float areaa = (ax2 - ax1 + 1.0f) * (ay2 - ay1 + 1.0f);

    // fg <=> exists g with RN(inter/denom) >= 0.5
    //     <=> inter >= denom * (0.5 - 2^-26), EXACT in double.
    int fg = 0;
#pragma unroll 4
    for (int g = 0; g < G; ++g) {
      const float4 gb = gbox[g];
      const float gar = garea[g];
      float iw = fminf(ax2, gb.z) - fmaxf(ax1, gb.x) + 1.0f;
      iw = fmaxf(iw, 0.0f);
      float ih = fminf(ay2, gb.w) - fmaxf(ay1, gb.y) + 1.0f;
      ih = fmaxf(ih, 0.0f);
      float inter = iw * ih;
      float denom = (areaa + gar) - inter;   // > 0 always
      fg |= ((double)inter >= (double)denom * 0x1.ffffffp-2);
    }
    // bg = !fg exactly

    u32 kb0, kb1, k10, k11, k20, k21;
    batch_key(b, kb0, kb1);
    sub_key(kb0, kb1, 0, k10, k11);
    sub_key(kb0, kb1, 1, k20, k21);
    if (valid) {
      u32 kk0 = fg ? k10 : k20;
      u32 kk1 = fg ? k11 : k21;
      u32 key = rand_bits(kk0, kk1, n) >> 9;   // 23-bit mantissa order
      u32 set = fg ? 0u : 1u;
      ckey[(size_t)b * N + n] = key | (set << 31);
      atomicAdd((unsigned int*)&cnt[((size_t)b * 2 + set) * NBKT + (key >> 10)], 1u);
    }

    u32 vF = (valid && !fg) ? (u32)n : SENT;
    u32 vB = (valid &&  fg) ? (u32)n : SENT;
#pragma unroll
    for (int m = 1; m <= 32; m <<= 1) {
      vF = min(vF, (u32)__shfl_xor((int)vF, m));
      vB = min(vB, (u32)__shfl_xor((int)vB, m));
    }
    if ((tid & 63) == 0) { wminF[tid >> 6] = vF; wminB[tid >> 6] = vB; }
    __syncthreads();
    if (tid == 0) {
      u32 mF = SENT, mB = SENT;
#pragma unroll
      for (int w = 0; w < TPB / 64; ++w) { mF = min(mF, wminF[w]); mB = min(mB, wminB[w]); }
      minblkF[b * NBLK + x] = mF;
      minblkB[b * NBLK + x] = mB;
    }
  }
  grid.sync();

  // ---------- phase 2: scan (blocks 0..31) ----------
  if (blk < B * 2) {
    constexpr int PER = NBKT / TPB;   // 32
    const int sb = blk >> 1, set = blk & 1;
    u32* c = cnt + ((size_t)sb * 2 + set) * NBKT;
    u32* q = cur + ((size_t)sb * 2 + set) * NBKT;
    u32 local[PER];
    u32 tot = 0;
    const int base = tid * PER;
#pragma unroll
    for (int i = 0; i < PER; ++i) { u32 v = c[base + i]; local[i] = tot; tot += v; }
    sh[tid] = tot;
    __syncthreads();
    for (int off = 1; off < TPB; off <<= 1) {
      u32 v = (tid >= off) ? sh[tid - off] : 0u;
      __syncthreads();
      sh[tid] += v;
      __syncthreads();
    }
    const u32 pre = sh[tid] - tot;
    const u32 total = sh[TPB - 1];
#pragma unroll
    for (int i = 0; i < PER; ++i) { u32 v = pre + local[i]; c[base + i] = v; q[base + i] = v; }

    if (tid < 64) {
      const u32* mb = (set ? minblkB : minblkF) + sb * NBLK;
      u32 m = SENT;
      for (int i = tid; i < NBLK; i += 64) m = min(m, mb[i]);
#pragma unroll
      for (int mm = 1; mm <= 32; mm <<= 1) m = min(m, (u32)__shfl_xor((int)m, mm));
      if (tid == 0) {
        u32* slot = (set ? slotB : slotF) + (size_t)sb * N;
        if (total < (u32)N) slot[total] = (m == SENT) ? 0u : m;  // rank-total entry
        if (set) nbg[sb] = (int)total; else nfg[sb] = (int)total;
      }
    }
  }
  grid.sync();

  // ---------- phase 3: scatter ----------
  for (int c = blk; c < CHNK; c += GRID) {
    const int b = c / NBLK;
    const int n = (c % NBLK) * TPB + tid;
    if (n < N) {
      const u32 w = ckey[(size_t)b * N + n];
      const u32 set = w >> 31;
      const u32 key = w & 0x7FFFFFu;
      u32 pos = atomicAdd((unsigned int*)&cur[((size_t)b * 2 + set) * NBKT + (key >> 10)], 1u);
      u32* slot = (set ? slotB : slotF) + (size_t)b * N;
      slot[pos] = ((key & 1023u) << 15) | (u32)n;
    }
  }
  grid.sync();

  // ---------- phase 4: bucket insertion sort (grid-stride; 262144 buckets) --
  for (int t = blk * TPB + tid; t < B * 2 * NBKT; t += GRID * TPB) {
    const int bs = t / NBKT;        // b*2+set
    u32* slot = ((bs & 1) ? slotB : slotF) + (size_t)(bs >> 1) * N;
    const u32 s0 = cnt[t];
    const u32 e = cur[t];
    for (u32 i = s0 + 1; i < e; ++i) {
      u32 v = slot[i];
      int j = (int)i - 1;
      while (j >= (int)s0 && slot[j] > v) { slot[j + 1] = slot[j]; --j; }
      slot[j + 1] = v;
    }
  }
  grid.sync();

  // ---------- phase 5: sample (blocks 0..31, 256 slots each) ----------
  if (blk < B * 2) {
    const int pb = blk >> 1;
    const int s = (blk & 1) * TPB + tid;   // 0..511
    __syncthreads();   // fence phase-1 LDS reuse
    if (tid < G) {
      const float* gp = gts + (size_t)(pb * G + tid) * 5;
      float x1 = gp[0], y1 = gp[1], x2 = gp[2], y2 = gp[3];
      gbox[tid] = make_float4(x1, y1, x2, y2);
      garea[tid] = (x2 - x1 + 1.0f) * (y2 - y1 + 1.0f);
      glab[tid] = gp[4];
    }
    __syncthreads();

    const int nfgv = nfg[pb];
    const int nbgv = nbg[pb];

    u32 kb0, kb1, k30, k31, k40, k41;
    batch_key(pb, kb0, kb1);
    sub_key(kb0, kb1, 2, k30, k31);
    sub_key(kb0, kb1, 3, k40, k41);
    float rf = bits_to_uniform(rand_bits(k30, k31, s));
    float rb = bits_to_uniform(rand_bits(k40, k41, s));

    int n_fg_take = (nbgv > 0) ? min(KFG, nfgv) : S;
    if (nfgv <= 0) n_fg_take = 0;

    int keep;
    if (s < n_fg_take) {
      int fi;
      if (nbgv > 0) fi = s;                      // s < n_fg_take <= nfg
      else {
        fi = (int)(rf * (float)nfgv);            // f32 mul, trunc
        fi = max(0, min(fi, nfgv));              // rank nfg = sentinel entry
      }
      keep = (int)(slotF[(size_t)pb * N + fi] & 0x7FFFu);
    } else {
      if (nbgv > 0) {
        int bi = (int)(rb * (float)nbgv);
        bi = max(0, min(bi, nbgv));              // rank nbg = sentinel entry
        keep = (int)(slotB[(size_t)pb * N + bi] & 0x7FFFu);
      } else {
        keep = 0;  // all-sentinel stable argsort -> identity -> index 0
      }
    }
    keep = max(0, min(keep, N - 1));

    float ax1, ay1, ax2, ay2;
    if (keep < R) {
      const float* rp = rois + (size_t)(pb * R + keep) * 5;
      ax1 = rp[1]; ay1 = rp[2]; ax2 = rp[3]; ay2 = rp[4];
    } else {
      const float4 g2 = gbox[keep - R];
      ax1 = g2.x; ay1 = g2.y; ax2 = g2.z; ay2 = g2.w;
    }
    const float areaa = (ax2 - ax1 + 1.0f) * (ay2 - ay1 + 1.0f);

    // exact argmax (first occurrence of max), IEEE divide — 512/batch only
    float best = -1.0f;
    int arg = 0;
    for (int g = 0; g < G; ++g) {
      const float4 gb = gbox[g];
      const float gar = garea[g];
      float iw = fminf(ax2, gb.z) - fmaxf(ax1, gb.x) + 1.0f;
      iw = fmaxf(iw, 0.0f);
      float ih = fminf(ay2, gb.w) - fmaxf(ay1, gb.y) + 1.0f;
      ih = fmaxf(ih, 0.0f);
      float inter = iw * ih;
      float denom = (areaa + gar) - inter;
      float iou = inter / denom;                 // IEEE, bit-exact
      if (iou > best) { best = iou; arg = g; }
    }

    const bool isfg = s < n_fg_take;
    const float label = isfg ? glab[arg] : 0.0f;
    const float4 gbx = gbox[arg];
    const float gx1 = gbx.x, gy1 = gbx.y, gx2 = gbx.z, gy2 = gbx.w;

    float ew = ax2 - ax1 + 1.0f, eh = ay2 - ay1 + 1.0f;
    float ecx = ax1 + 0.5f * ew, ecy = ay1 + 0.5f * eh;
    float gw = gx2 - gx1 + 1.0f, gh = gy2 - gy1 + 1.0f;
    float gcx = gx1 + 0.5f * gw, gcy = gy1 + 0.5f * gh;
    float t0 = (gcx - ecx) / ew;
    float t1 = (gcy - ecy) / eh;
    float t2 = logf(gw / ew);
    float t3 = logf(gh / eh);
    const float msk = (label > 0.0f) ? 1.0f : 0.0f;
    t0 = (t0 - means[0]) / stds[0] * msk;
    t1 = (t1 - means[1]) / stds[1] * msk;
    t2 = (t2 - means[2]) / stds[2] * msk;
    t3 = (t3 - means[3]) / stds[3] * msk;

    float* rout = out;                        // [B,S,5]
    float* lout = out + (size_t)B * S * 5;    // [B,S]
    float* tout = lout + (size_t)B * S;       // [B,S,4]
    float* rp2 = rout + (size_t)(pb * S + s) * 5;
    rp2[0] = (float)pb;
    rp2[1] = ax1; rp2[2] = ay1; rp2[3] = ax2; rp2[4] = ay2;
    lout[pb * S + s] = label;
    float* tp = tout + (size_t)(pb * S + s) * 4;
    tp[0] = t0; tp[1] = t1; tp[2] = t2; tp[3] = t3;
  }
}

// ---------------- launch ----------------
extern "C" void kernel_launch(void* const* d_in, const int* in_sizes, int n_in,
                              void* d_out, int out_size, void* d_ws, size_t ws_size,
                              hipStream_t stream) {
  const float* rois  = (const float*)d_in[0];
  const float* gts   = (const float*)d_in[1];
  const float* means = (const float*)d_in[2];
  const float* stds  = (const float*)d_in[3];

  char* ws = (char*)d_ws;
  const size_t per = (size_t)B * N;
  const size_t bkts = (size_t)B * 2 * NBKT;   // 262144 u32 = 1 MB
  u32* ckey    = (u32*)ws; ws += per * sizeof(u32);
  u32* slotF   = (u32*)ws; ws += per * sizeof(u32);
  u32* slotB   = (u32*)ws; ws += per * sizeof(u32);
  u32* cnt     = (u32*)ws; ws += bkts * sizeof(u32);   // hist -> bases
  u32* cur     = (u32*)ws; ws += bkts * sizeof(u32);   // cursors -> ends
  u32* minblkF = (u32*)ws; ws += (size_t)B * NBLK * sizeof(u32);
  u32* minblkB = (u32*)ws; ws += (size_t)B * NBLK * sizeof(u32);
  int* nfg     = (int*)ws; ws += B * sizeof(int);
  int* nbg     = (int*)ws; ws += B * sizeof(int);
  float* outp  = (float*)d_out;

  void* args[] = {&rois, &gts, &means, &stds, &ckey, &cnt, &cur,
                  &minblkF, &minblkB, &nfg, &nbg, &slotF, &slotB, &outp};
  hipLaunchCooperativeKernel((const void*)k_fused, dim3(GRID), dim3(TPB),
                             args, 0, stream);
}

// Round 16
// 77.404 us; speedup vs baseline: 4.5885x; 4.5885x over previous
//
#include <hip/hip_runtime.h>
#include <stdint.h>

// buildProposalTargetLayer — exact JAX replication (partitionable threefry).
// R16 = revert to R12 (proven best: 77.97us, absmax 0.0).
// Cooperative fusion was falsified: R15's grid.sync() costs ~60us each on
// MI355X (cross-XCD L2 writeback/invalidate per sync; 8 XCDs, non-coherent
// L2s) -> 342us fused vs 38.5us unfused pipeline. Kernel boundaries are the
// cheap ordering primitive on this chip.
// The per-iteration 256MiB harness ws-poison fill (~39.5us @86% HBM peak) is
// fixed overhead outside our control (~51% of total).
//   k_zero    : zero 1MB bucket histogram (uint4 stores)
//   k_mask    : 1 thr/ROI, divide-free EXACT fg test, one threefry key,
//               scattered hist atomic, per-block min non-candidate idx
//   k_scan    : 32 blocks x 1024 — scan hist -> bases(cnt)/cursors(cur),
//               totals, minblk reduce, rank-total sentinel entry
//   k_scatter : 1 load + 1 atomic + 1 store per ROI
//   k_bsort   : one thread per bucket insertion sort over [cnt[t], cur[t])
//   k_sample  : direct slot[rank] pick + inline exact argmax + encode

typedef uint32_t u32;

constexpr int B    = 16;
constexpr int R    = 20000;
constexpr int G    = 100;
constexpr int N    = R + G;    // 20100
constexpr int S    = 512;
constexpr int KFG  = 128;
constexpr int NBKT = 8192;     // bucket = key>>10 (23-bit keys), avg ~2.5/bucket
constexpr u32 SENT = 0xFFFFFFFFu;
constexpr int TPB  = 256;
constexpr int NBLK = (N + TPB - 1) / TPB;   // 79 blocks per batch in k_mask

// ---------------- threefry2x32 (20 rounds) ----------------
__device__ __forceinline__ void tf2x32(u32 k0, u32 k1, u32 x0, u32 x1,
                                       u32& o0, u32& o1) {
  u32 ks2 = k0 ^ k1 ^ 0x1BD11BDAu;
#define TFR(r) { x0 += x1; x1 = (x1 << (r)) | (x1 >> (32 - (r))); x1 ^= x0; }
  x0 += k0; x1 += k1;
  TFR(13) TFR(15) TFR(26) TFR(6)
  x0 += k1;  x1 += ks2 + 1u;
  TFR(17) TFR(29) TFR(16) TFR(24)
  x0 += ks2; x1 += k0 + 2u;
  TFR(13) TFR(15) TFR(26) TFR(6)
  x0 += k0;  x1 += k1 + 3u;
  TFR(17) TFR(29) TFR(16) TFR(24)
  x0 += k1;  x1 += ks2 + 4u;
  TFR(13) TFR(15) TFR(26) TFR(6)
  x0 += ks2; x1 += k0 + 5u;
#undef TFR
  o0 = x0; o1 = x1;
}

__device__ __forceinline__ void batch_key(int b, u32& kb0, u32& kb1) {
  tf2x32(0u, 42u, 0u, (u32)b, kb0, kb1);
}
__device__ __forceinline__ void sub_key(u32 kb0, u32 kb1, int j, u32& k0, u32& k1) {
  tf2x32(kb0, kb1, 0u, (u32)j, k0, k1);
}
__device__ __forceinline__ u32 rand_bits(u32 k0, u32 k1, int i) {
  u32 b0, b1;
  tf2x32(k0, k1, 0u, (u32)i, b0, b1);
  return b0 ^ b1;
}
__device__ __forceinline__ float bits_to_uniform(u32 bits) {
  return __uint_as_float((bits >> 9) | 0x3f800000u) - 1.0f;
}

// ---------------- k_zero: 1MB histogram zero ----------------
__global__ __launch_bounds__(256) void k_zero(uint4* __restrict__ p) {
  p[blockIdx.x * 256 + threadIdx.x] = make_uint4(0u, 0u, 0u, 0u);
}

// ---------------- k_mask: 1 thread per ROI, divide-free fg test -----------
__global__ __launch_bounds__(TPB) void
k_mask(const float* __restrict__ rois, const float* __restrict__ gts,
       u32* __restrict__ ckey, u32* __restrict__ cnt,
       u32* __restrict__ minblkF, u32* __restrict__ minblkB) {
#pragma clang fp contract(off)
  __shared__ float4 gbox[G];
  __shared__ float garea[G];
  __shared__ u32 wminF[TPB / 64], wminB[TPB / 64];
  const int b = blockIdx.y;
  if (threadIdx.x < G) {
    const float* gp = gts + (size_t)(b * G + threadIdx.x) * 5;
    float x1 = gp[0], y1 = gp[1], x2 = gp[2], y2 = gp[3];
    gbox[threadIdx.x] = make_float4(x1, y1, x2, y2);
    garea[threadIdx.x] = (x2 - x1 + 1.0f) * (y2 - y1 + 1.0f);
  }
  __syncthreads();

  const int n = blockIdx.x * TPB + threadIdx.x;
  const bool valid = n < N;
  const int nl = valid ? n : 0;

  float ax1, ay1, ax2, ay2;
  if (nl < R) {
    const float* rp = rois + (size_t)(b * R + nl) * 5;
    ax1 = rp[1]; ay1 = rp[2]; ax2 = rp[3]; ay2 = rp[4];
  } else {
    const float* gp = gts + (size_t)(b * G + (nl - R)) * 5;
    ax1 = gp[0]; ay1 = gp[1]; ax2 = gp[2]; ay2 = gp[3];
  }
  const float areaa = (ax2 - ax1 + 1.0f) * (ay2 - ay1 + 1.0f);

  // fg <=> exists g with RN(inter/denom) >= 0.5
  //     <=> inter >= denom * (0.5 - 2^-26), evaluated EXACTLY in double.
  int fg = 0;
#pragma unroll 4
  for (int g = 0; g < G; ++g) {
    const float4 gb = gbox[g];
    const float gar = garea[g];
    float iw = fminf(ax2, gb.z) - fmaxf(ax1, gb.x) + 1.0f;
    iw = fmaxf(iw, 0.0f);
    float ih = fminf(ay2, gb.w) - fmaxf(ay1, gb.y) + 1.0f;
    ih = fmaxf(ih, 0.0f);
    float inter = iw * ih;
    float denom = (areaa + gar) - inter;   // > 0 always (areas >= 1)
    fg |= ((double)inter >= (double)denom * 0x1.ffffffp-2);
  }
  // bg = !fg exactly

  u32 kb0, kb1, k10, k11, k20, k21;
  batch_key(b, kb0, kb1);            // uniform -> SALU
  sub_key(kb0, kb1, 0, k10, k11);
  sub_key(kb0, kb1, 1, k20, k21);
  if (valid) {
    // ONE threefry: select the key pair by set (bits identical to both)
    u32 kk0 = fg ? k10 : k20;
    u32 kk1 = fg ? k11 : k21;
    u32 key = rand_bits(kk0, kk1, n) >> 9;   // 23-bit mantissa bits = float order
    u32 set = fg ? 0u : 1u;
    ckey[(size_t)b * N + n] = key | (set << 31);
    atomicAdd((unsigned int*)&cnt[((size_t)b * 2 + set) * NBKT + (key >> 10)], 1u);
  }

  // per-block min non-candidate index (plain stores; reduced in k_scan)
  u32 vF = (valid && !fg) ? (u32)n : SENT;  // non-candidates of fg set
  u32 vB = (valid &&  fg) ? (u32)n : SENT;  // non-candidates of bg set
#pragma unroll
  for (int m = 1; m <= 32; m <<= 1) {
    vF = min(vF, (u32)__shfl_xor((int)vF, m));
    vB = min(vB, (u32)__shfl_xor((int)vB, m));
  }
  if ((threadIdx.x & 63) == 0) {
    wminF[threadIdx.x >> 6] = vF;
    wminB[threadIdx.x >> 6] = vB;
  }
  __syncthreads();
  if (threadIdx.x == 0) {
    u32 mF = SENT, mB = SENT;
#pragma unroll
    for (int w = 0; w < TPB / 64; ++w) { mF = min(mF, wminF[w]); mB = min(mB, wminB[w]); }
    minblkF[b * NBLK + blockIdx.x] = mF;
    minblkB[b * NBLK + blockIdx.x] = mB;
  }
}

// ------- k_scan: hist scan -> bases/cursors, totals, sentinel entry --------
__global__ __launch_bounds__(1024) void
k_scan(u32* __restrict__ cnt, u32* __restrict__ cur,
       int* __restrict__ nfg, int* __restrict__ nbg,
       const u32* __restrict__ minblkF, const u32* __restrict__ minblkB,
       u32* __restrict__ slotF, u32* __restrict__ slotB) {
  constexpr int T = 1024;
  constexpr int PER = NBKT / T;   // 8
  __shared__ u32 sh[T];
  const int b = blockIdx.x, set = blockIdx.y;
  const int tid = threadIdx.x;
  u32* c = cnt + ((size_t)b * 2 + set) * NBKT;
  u32* q = cur + ((size_t)b * 2 + set) * NBKT;
  u32 local[PER];
  u32 tot = 0;
  const int base = tid * PER;
#pragma unroll
  for (int i = 0; i < PER; ++i) { u32 v = c[base + i]; local[i] = tot; tot += v; }
  sh[tid] = tot;
  __syncthreads();
  for (int off = 1; off < T; off <<= 1) {
    u32 v = (tid >= off) ? sh[tid - off] : 0u;
    __syncthreads();
    sh[tid] += v;
    __syncthreads();
  }
  const u32 pre = sh[tid] - tot;
  const u32 total = sh[T - 1];
#pragma unroll
  for (int i = 0; i < PER; ++i) { u32 v = pre + local[i]; c[base + i] = v; q[base + i] = v; }

  // wave 0: reduce per-block mins; lane 0 writes sentinel + totals
  if (tid < 64) {
    const u32* mb = (set ? minblkB : minblkF) + b * NBLK;
    u32 m = SENT;
    for (int i = tid; i < NBLK; i += 64) m = min(m, mb[i]);
#pragma unroll
    for (int mm = 1; mm <= 32; mm <<= 1) m = min(m, (u32)__shfl_xor((int)m, mm));
    if (tid == 0) {
      u32* slot = (set ? slotB : slotF) + (size_t)b * N;
      if (total < (u32)N) slot[total] = (m == SENT) ? 0u : m;  // rank-total entry
      if (set) nbg[b] = (int)total; else nfg[b] = (int)total;
    }
  }
}

// ---------------- k_scatter: 1 load + 1 atomic + 1 store per ROI ----------
__global__ void k_scatter(const u32* __restrict__ ckey, u32* __restrict__ cur,
                          u32* __restrict__ slotF, u32* __restrict__ slotB) {
  const int b = blockIdx.y;
  const int n = blockIdx.x * blockDim.x + threadIdx.x;
  if (n >= N) return;
  const u32 w = ckey[(size_t)b * N + n];
  const u32 set = w >> 31;
  const u32 key = w & 0x7FFFFFu;
  u32 pos = atomicAdd((unsigned int*)&cur[((size_t)b * 2 + set) * NBKT + (key >> 10)], 1u);
  u32* slot = (set ? slotB : slotF) + (size_t)b * N;
  slot[pos] = ((key & 1023u) << 15) | (u32)n;
}

// ---------------- k_bsort: one thread per bucket, range [cnt[t], cur[t]) ----
__global__ void k_bsort(const u32* __restrict__ cnt /*bases*/,
                        const u32* __restrict__ cur /*ends*/,
                        u32* __restrict__ slotF, u32* __restrict__ slotB) {
  const int t = blockIdx.x * blockDim.x + threadIdx.x;
  const int total = B * 2 * NBKT;
  if (t >= total) return;
  const int bs = t / NBKT;        // b*2+set
  u32* slot = ((bs & 1) ? slotB : slotF) + (size_t)(bs >> 1) * N;
  const u32 s0 = cnt[t];
  const u32 e = cur[t];
  for (u32 i = s0 + 1; i < e; ++i) {
    u32 v = slot[i];
    int j = (int)i - 1;
    while (j >= (int)s0 && slot[j] > v) { slot[j + 1] = slot[j]; --j; }
    slot[j + 1] = v;
  }
}

// ---------------- k_sample: direct slot[rank] + exact argmax + encode ------
__global__ __launch_bounds__(128) void
k_sample(const float* __restrict__ rois, const float* __restrict__ gts,
         const float* __restrict__ means, const float* __restrict__ stds,
         const int* __restrict__ nfgA, const int* __restrict__ nbgA,
         const u32* __restrict__ slotF, const u32* __restrict__ slotB,
         float* __restrict__ out) {
#pragma clang fp contract(off)
  __shared__ float4 gbox[G];
  __shared__ float garea[G];
  __shared__ float glab[G];
  const int b = blockIdx.x;
  const int s = blockIdx.y * 128 + threadIdx.x;
  if (threadIdx.x < G) {
    const float* gp = gts + (size_t)(b * G + threadIdx.x) * 5;
    float x1 = gp[0], y1 = gp[1], x2 = gp[2], y2 = gp[3];
    gbox[threadIdx.x] = make_float4(x1, y1, x2, y2);
    garea[threadIdx.x] = (x2 - x1 + 1.0f) * (y2 - y1 + 1.0f);
    glab[threadIdx.x] = gp[4];
  }
  __syncthreads();

  const int nfg = nfgA[b];
  const int nbg = nbgA[b];

  u32 kb0, kb1, k30, k31, k40, k41;
  batch_key(b, kb0, kb1);
  sub_key(kb0, kb1, 2, k30, k31);
  sub_key(kb0, kb1, 3, k40, k41);
  float rf = bits_to_uniform(rand_bits(k30, k31, s));
  float rb = bits_to_uniform(rand_bits(k40, k41, s));

  int n_fg_take = (nbg > 0) ? min(KFG, nfg) : S;
  if (nfg <= 0) n_fg_take = 0;

  int keep;
  if (s < n_fg_take) {
    int fi;
    if (nbg > 0) fi = s;                       // s < n_fg_take <= nfg
    else {
      fi = (int)(rf * (float)nfg);             // f32 mul, trunc
      fi = max(0, min(fi, nfg));               // rank nfg = sentinel entry (exact)
    }
    keep = (int)(slotF[(size_t)b * N + fi] & 0x7FFFu);
  } else {
    if (nbg > 0) {
      int bi = (int)(rb * (float)nbg);
      bi = max(0, min(bi, nbg));               // rank nbg = sentinel entry (exact)
      keep = (int)(slotB[(size_t)b * N + bi] & 0x7FFFu);
    } else {
      keep = 0;  // all-sentinel stable argsort -> identity -> index 0
    }
  }
  keep = max(0, min(keep, N - 1));

  // ROI box of keep
  float ax1, ay1, ax2, ay2;
  if (keep < R) {
    const float* rp = rois + (size_t)(b * R + keep) * 5;
    ax1 = rp[1]; ay1 = rp[2]; ax2 = rp[3]; ay2 = rp[4];
  } else {
    const float4 g2 = gbox[keep - R];
    ax1 = g2.x; ay1 = g2.y; ax2 = g2.z; ay2 = g2.w;
  }
  const float areaa = (ax2 - ax1 + 1.0f) * (ay2 - ay1 + 1.0f);

  // exact argmax (first occurrence of max), IEEE divide — 512/batch only
  float best = -1.0f;
  int arg = 0;
  for (int g = 0; g < G; ++g) {
    const float4 gb = gbox[g];
    const float gar = garea[g];
    float iw = fminf(ax2, gb.z) - fmaxf(ax1, gb.x) + 1.0f;
    iw = fmaxf(iw, 0.0f);
    float ih = fminf(ay2, gb.w) - fmaxf(ay1, gb.y) + 1.0f;
    ih = fmaxf(ih, 0.0f);
    float inter = iw * ih;
    float denom = (areaa + gar) - inter;
    float iou = inter / denom;                 // IEEE, bit-exact
    if (iou > best) { best = iou; arg = g; }
  }

  const bool isfg = s < n_fg_take;
  const float label = isfg ? glab[arg] : 0.0f;
  const float4 gbx = gbox[arg];
  const float gx1 = gbx.x, gy1 = gbx.y, gx2 = gbx.z, gy2 = gbx.w;

  float ew = ax2 - ax1 + 1.0f, eh = ay2 - ay1 + 1.0f;
  float ecx = ax1 + 0.5f * ew, ecy = ay1 + 0.5f * eh;
  float gw = gx2 - gx1 + 1.0f, gh = gy2 - gy1 + 1.0f;
  float gcx = gx1 + 0.5f * gw, gcy = gy1 + 0.5f * gh;
  float t0 = (gcx - ecx) / ew;
  float t1 = (gcy - ecy) / eh;
  float t2 = logf(gw / ew);
  float t3 = logf(gh / eh);
  const float msk = (label > 0.0f) ? 1.0f : 0.0f;
  t0 = (t0 - means[0]) / stds[0] * msk;
  t1 = (t1 - means[1]) / stds[1] * msk;
  t2 = (t2 - means[2]) / stds[2] * msk;
  t3 = (t3 - means[3]) / stds[3] * msk;

  float* rout = out;                        // [B,S,5]
  float* lout = out + (size_t)B * S * 5;    // [B,S]
  float* tout = lout + (size_t)B * S;       // [B,S,4]
  float* rp2 = rout + (size_t)(b * S + s) * 5;
  rp2[0] = (float)b;
  rp2[1] = ax1; rp2[2] = ay1; rp2[3] = ax2; rp2[4] = ay2;
  lout[b * S + s] = label;
  float* tp = tout + (size_t)(b * S + s) * 4;
  tp[0] = t0; tp[1] = t1; tp[2] = t2; tp[3] = t3;
}

// ---------------- launch ----------------
extern "C" void kernel_launch(void* const* d_in, const int* in_sizes, int n_in,
                              void* d_out, int out_size, void* d_ws, size_t ws_size,
                              hipStream_t stream) {
  const float* rois  = (const float*)d_in[0];
  const float* gts   = (const float*)d_in[1];
  const float* means = (const float*)d_in[2];
  const float* stds  = (const float*)d_in[3];

  char* ws = (char*)d_ws;
  const size_t per = (size_t)B * N;
  const size_t bkts = (size_t)B * 2 * NBKT;   // 262144 u32 = 1 MB
  u32* ckey    = (u32*)ws; ws += per * sizeof(u32);
  u32* slotF   = (u32*)ws; ws += per * sizeof(u32);
  u32* slotB   = (u32*)ws; ws += per * sizeof(u32);
  u32* cnt     = (u32*)ws; ws += bkts * sizeof(u32);   // hist -> bases
  u32* cur     = (u32*)ws; ws += bkts * sizeof(u32);   // cursors -> ends
  u32* minblkF = (u32*)ws; ws += (size_t)B * NBLK * sizeof(u32);
  u32* minblkB = (u32*)ws; ws += (size_t)B * NBLK * sizeof(u32);
  int* nfg     = (int*)ws; ws += B * sizeof(int);
  int* nbg     = (int*)ws; ws += B * sizeof(int);

  hipLaunchKernelGGL(k_zero, dim3((int)(bkts / 4 / 256)), dim3(256), 0, stream,
                     (uint4*)cnt);
  hipLaunchKernelGGL(k_mask, dim3(NBLK, B), dim3(TPB), 0, stream,
                     rois, gts, ckey, cnt, minblkF, minblkB);
  hipLaunchKernelGGL(k_scan, dim3(B, 2), dim3(1024), 0, stream,
                     cnt, cur, nfg, nbg, minblkF, minblkB, slotF, slotB);
  hipLaunchKernelGGL(k_scatter, dim3((N + 255) / 256, B), dim3(256), 0, stream,
                     ckey, cur, slotF, slotB);
  hipLaunchKernelGGL(k_bsort, dim3((B * 2 * NBKT + 255) / 256), dim3(256), 0, stream,
                     cnt, cur, slotF, slotB);
  hipLaunchKernelGGL(k_sample, dim3(B, S / 128), dim3(128), 0, stream,
                     rois, gts, means, stds, nfg, nbg, slotF, slotB,
                     (float*)d_out);
}